// Round 9
// baseline (3707.153 us; speedup 1.0000x reference)
//
#include <hip/hip_runtime.h>
#include <hip/hip_bf16.h>

typedef short  bf16x8 __attribute__((ext_vector_type(8)));
typedef float  f32x4  __attribute__((ext_vector_type(4)));
typedef int    i32x4  __attribute__((ext_vector_type(4)));

#define BB 64
#define SS 512
#define EE 300
#define HH 512

// workspace layout (bytes)
#define XT_OFF      ((size_t)0)
#define XT_BYTES    ((size_t)SS*10*4*1024)       // 20,971,520  x tiles [t][ks10][mt4][1KB]
#define SLOT_OFF    (XT_OFF + XT_BYTES)
#define PLANE_B     ((size_t)64*128*16)          // 131,072 per plane: [s64][uq128] 16B slots
#define SLOT_BYTES  ((size_t)4*PLANE_B)          // 524,288 (4 planes, mod-4 tags)
#define HT_OFF      (SLOT_OFF + SLOT_BYTES)
#define HT_BYTES    ((size_t)BB*HH*4)            // 131,072

__device__ __forceinline__ unsigned short f2bf(float x) {
  union { float f; unsigned u; } v; v.f = x;
  unsigned r = v.u + 0x7fffu + ((v.u >> 16) & 1u);   // RNE
  return (unsigned short)(r >> 16);
}
__device__ __forceinline__ float sigm(float x) { return 1.f / (1.f + __expf(-x)); }
__device__ __forceinline__ float tanh_fast(float x) { return 1.f - 2.f / (__expf(2.f * x) + 1.f); }

// ---- phase 0: embedding gather + cast, fragment-tiled output (proven R5-R7) ----
// block layout: [t][ks(10)][mt(4)] of 1KB; within block [c(16)][kg(4)][j(8)] bf16
__global__ void gather_cast_kernel(const int* __restrict__ idx,
                                   const float* __restrict__ emb,
                                   unsigned short* __restrict__ xt) {
  __shared__ unsigned short lds_x[16 * 320];
  const int t     = blockIdx.x >> 2;
  const int mtile = blockIdx.x & 3;
  const int tid   = threadIdx.x;                 // 0..255

  const int c2 = tid >> 4;
  const int e0 = tid & 15;
  const int b  = mtile * 16 + c2;
  const int vocab = idx[b * SS + t];
  const float* src = emb + (size_t)vocab * EE;
  for (int e = e0; e < 320; e += 16)
    lds_x[c2 * 320 + e] = (e < EE) ? f2bf(src[e]) : (unsigned short)0;
  __syncthreads();

  unsigned short* outb = xt + (((size_t)t * 10) * 4 + mtile) * 512;
  #pragma unroll
  for (int rr = 0; rr < 3; ++rr) {
    int O = rr * 4096 + tid * 16;                // byte offset within 10KB
    if (O < 10240) {
      int ks = O >> 10;
      int inblk = O & 1023;
      int c  = inblk >> 6;
      int kg = (inblk >> 4) & 3;
      bf16x8 v = *(const bf16x8*)&lds_x[c * 320 + ks * 32 + kg * 8];
      *(bf16x8*)((char*)outb + (size_t)ks * 4096 + inblk) = v;
    }
  }
}

// ---- phase 1: persistent recurrence, 256 fully-independent waves ----
// Wave (p, mt): units 8p..8p+7 (2 col-tiles of 4), samples 16mt..+15, FULL K.
// No LDS, no barriers, no intra-wg coupling. Tagged 16B slots {8B = 4 units
// bf16, 4B tag, 4B pad}; tag rides with data (single atomic 16B store) so
// producers never drain-before-flag; consumers poll-load speculatively.
// Slot plane: [s64][uq128], 4 planes indexed (it&3), tag value = it.
__launch_bounds__(64, 1)
__global__ void lstm_kernel(const unsigned short* __restrict__ xt,
                            char* __restrict__ slots,
                            float* __restrict__ hT,
                            const float* __restrict__ Wih,
                            const float* __restrict__ Whh,
                            const float* __restrict__ bih,
                            const float* __restrict__ bhh) {
  const int p  = blockIdx.x >> 2;          // 0..63: units 8p..8p+7
  const int mt = blockIdx.x & 3;           // m-tile: samples 16mt..16mt+15
  const int l  = threadIdx.x;              // 0..63
  const int c  = l & 15;                   // col: gate=c>>2, unit-in-quad=c&3
  const int kg = l >> 4;                   // k-group

  // ---- preload W fragments, both col-tiles, full K (constant all steps) ----
  const int G0 = ((c >> 2) << 9) + (p << 3) + (c & 3);   // tile 0: units 8p..+3
  const int G1 = G0 + 4;                                 // tile 1: units 8p+4..+7
  bf16x8 Bx0[10], Bx1[10], Bh0[16], Bh1[16];
  {
    const float* w0 = Wih + (size_t)G0 * EE;
    const float* w1 = Wih + (size_t)G1 * EE;
    #pragma unroll
    for (int ks = 0; ks < 10; ++ks) {
      int k0 = 32 * ks + 8 * kg;
      bf16x8 v0, v1;
      #pragma unroll
      for (int j = 0; j < 8; ++j) {
        int k = k0 + j;
        v0[j] = (short)((k < EE) ? f2bf(w0[k]) : (unsigned short)0);
        v1[j] = (short)((k < EE) ? f2bf(w1[k]) : (unsigned short)0);
      }
      Bx0[ks] = v0; Bx1[ks] = v1;
    }
    const float* h0 = Whh + (size_t)G0 * HH;
    const float* h1 = Whh + (size_t)G1 * HH;
    #pragma unroll
    for (int ks = 0; ks < 16; ++ks) {
      int k0 = 32 * ks + 8 * kg;
      bf16x8 v0, v1;
      #pragma unroll
      for (int j = 0; j < 8; ++j) {
        v0[j] = (short)f2bf(h0[k0 + j]);
        v1[j] = (short)f2bf(h1[k0 + j]);
      }
      Bh0[ks] = v0; Bh1[ks] = v1;
    }
  }
  const float bc0 = bih[G0] + bhh[G0];
  const float bc1 = bih[G1] + bhh[G1];

  // addressing
  const unsigned short* xbase = xt + mt * 512 + c * 32 + kg * 8;   // ushort units
  const int rb = (16 * mt + c) * 2048 + kg * 32;   // consumer: + ks*128 (+16)
  const int wb = (16 * mt) * 2048 + 2 * p * 16;    // producer: + (4kg+r)*2048 + T*16
  float cst0[4] = {0.f, 0.f, 0.f, 0.f};
  float cst1[4] = {0.f, 0.f, 0.f, 0.f};

  for (int it = 0; it < SS; ++it) {
    // --- issue x loads (plain, cached), then speculative slot loads ---
    const unsigned short* xq = xbase + (size_t)it * 20480;
    bf16x8 xa[10];
    #pragma unroll
    for (int ks = 0; ks < 10; ++ks)
      asm volatile("global_load_dwordx4 %0, %1, off"
                   : "=v"(xa[ks]) : "v"(xq + ks * 2048) : "memory");

    const char* rp = slots + (size_t)(it & 3) * PLANE_B + rb;
    i32x4 sA[16], sB[16];
    #pragma unroll
    for (int ks = 0; ks < 16; ++ks) {
      asm volatile("global_load_dwordx4 %0, %1, off sc0 sc1"
                   : "=v"(sA[ks]) : "v"(rp + ks * 128) : "memory");
      asm volatile("global_load_dwordx4 %0, %1, off sc0 sc1"
                   : "=v"(sB[ks]) : "v"(rp + ks * 128 + 16) : "memory");
    }

    // --- x part: wait only the 10 x loads (32 slot loads still in flight) ---
    asm volatile("s_waitcnt vmcnt(32)" ::: "memory");
    __builtin_amdgcn_sched_barrier(0);
    f32x4 a0 = {bc0, bc0, bc0, bc0};     // bias folded into acc init
    f32x4 a1 = {bc1, bc1, bc1, bc1};
    #pragma unroll
    for (int ks = 0; ks < 10; ++ks) {
      a0 = __builtin_amdgcn_mfma_f32_16x16x32_bf16(xa[ks], Bx0[ks], a0, 0, 0, 0);
      a1 = __builtin_amdgcn_mfma_f32_16x16x32_bf16(xa[ks], Bx1[ks], a1, 0, 0, 0);
    }

    // --- tag-retry: the load IS the sync (in-band tags, no separate flag) ---
    asm volatile("s_waitcnt vmcnt(0)" ::: "memory");
    __builtin_amdgcn_sched_barrier(0);
    for (;;) {
      int ok = 1;
      #pragma unroll
      for (int ks = 0; ks < 16; ++ks)
        ok &= (sA[ks][2] == it) & (sB[ks][2] == it);
      if (__all(ok)) break;
      __builtin_amdgcn_s_sleep(1);
      #pragma unroll
      for (int ks = 0; ks < 16; ++ks) {
        asm volatile("global_load_dwordx4 %0, %1, off sc0 sc1"
                     : "=v"(sA[ks]) : "v"(rp + ks * 128) : "memory");
        asm volatile("global_load_dwordx4 %0, %1, off sc0 sc1"
                     : "=v"(sB[ks]) : "v"(rp + ks * 128 + 16) : "memory");
      }
      asm volatile("s_waitcnt vmcnt(0)" ::: "memory");
      __builtin_amdgcn_sched_barrier(0);
    }

    // --- h part: 32 MFMAs straight from slot registers ---
    #pragma unroll
    for (int ks = 0; ks < 16; ++ks) {
      i32x4 t;
      t[0] = sA[ks][0]; t[1] = sA[ks][1]; t[2] = sB[ks][0]; t[3] = sB[ks][1];
      bf16x8 a = __builtin_bit_cast(bf16x8, t);
      a0 = __builtin_amdgcn_mfma_f32_16x16x32_bf16(a, Bh0[ks], a0, 0, 0, 0);
      a1 = __builtin_amdgcn_mfma_f32_16x16x32_bf16(a, Bh1[ks], a1, 0, 0, 0);
    }

    // --- finalize in-register; tagged stores (tag rides with data) ---
    char* wp = slots + (size_t)((it + 1) & 3) * PLANE_B + wb;
    #pragma unroll
    for (int r = 0; r < 4; ++r) {
      {   // col-tile 0: units 8p..+3
        float v  = a0[r];
        float vf = __shfl_xor(v, 4, 64);
        float vg = __shfl_xor(v, 8, 64);
        float vo = __shfl_xor(v, 12, 64);
        float ig = sigm(v), fg = sigm(vf), og = sigm(vo), gt = tanh_fast(vg);
        cst0[r] = fg * cst0[r] + ig * gt;
        float h = og * tanh_fast(cst0[r]);
        if (it != SS - 1) {
          int hv  = (int)f2bf(h);
          int o1  = __shfl_xor(hv, 1, 64);
          int pk  = (hv & 0xffff) | (o1 << 16);
          int pk2 = __shfl_xor(pk, 2, 64);
          if (c == 0) {
            i32x4 val; val[0] = pk; val[1] = pk2; val[2] = it + 1; val[3] = 0;
            asm volatile("global_store_dwordx4 %0, %1, off sc0 sc1"
                         :: "v"(wp + (4 * kg + r) * 2048), "v"(val) : "memory");
          }
        } else if (c < 4) {
          hT[(size_t)(16 * mt + 4 * kg + r) * HH + (p << 3) + c] = h;
        }
      }
      {   // col-tile 1: units 8p+4..+7
        float v  = a1[r];
        float vf = __shfl_xor(v, 4, 64);
        float vg = __shfl_xor(v, 8, 64);
        float vo = __shfl_xor(v, 12, 64);
        float ig = sigm(v), fg = sigm(vf), og = sigm(vo), gt = tanh_fast(vg);
        cst1[r] = fg * cst1[r] + ig * gt;
        float h = og * tanh_fast(cst1[r]);
        if (it != SS - 1) {
          int hv  = (int)f2bf(h);
          int o1  = __shfl_xor(hv, 1, 64);
          int pk  = (hv & 0xffff) | (o1 << 16);
          int pk2 = __shfl_xor(pk, 2, 64);
          if (c == 0) {
            i32x4 val; val[0] = pk; val[1] = pk2; val[2] = it + 1; val[3] = 0;
            asm volatile("global_store_dwordx4 %0, %1, off sc0 sc1"
                         :: "v"(wp + (4 * kg + r) * 2048 + 16), "v"(val) : "memory");
          }
        } else if (c < 4) {
          hT[(size_t)(16 * mt + 4 * kg + r) * HH + (p << 3) + 4 + c] = h;
        }
      }
    }
  }
}

// ---- phase 2: y[b] = hT[b,:] . Wout + bout ----
__global__ void outproj_kernel(const float* __restrict__ hT,
                               const float* __restrict__ Wout,
                               const float* __restrict__ bout,
                               float* __restrict__ y) {
  int b = blockIdx.x;
  int t = threadIdx.x;   // 64
  float s = 0.f;
  for (int j = t; j < HH; j += 64) s += hT[b * HH + j] * Wout[j];
  #pragma unroll
  for (int off = 32; off > 0; off >>= 1) s += __shfl_down(s, off, 64);
  if (t == 0) y[b] = s + bout[0];
}

extern "C" void kernel_launch(void* const* d_in, const int* in_sizes, int n_in,
                              void* d_out, int out_size, void* d_ws, size_t ws_size,
                              hipStream_t stream) {
  const int*   idx  = (const int*)d_in[0];
  const float* emb  = (const float*)d_in[1];
  const float* Wih  = (const float*)d_in[2];
  const float* Whh  = (const float*)d_in[3];
  const float* bih  = (const float*)d_in[4];
  const float* bhh  = (const float*)d_in[5];
  const float* Wout = (const float*)d_in[6];
  const float* bout = (const float*)d_in[7];
  float* y = (float*)d_out;

  char* ws = (char*)d_ws;
  unsigned short* xt = (unsigned short*)(ws + XT_OFF);
  char* slots        = ws + SLOT_OFF;
  float* hT          = (float*)(ws + HT_OFF);

  // deterministic per-call init: all 4 planes zeroed (h(0)=0 with tag 0 in
  // plane 0; stale tags from previous graph replay killed everywhere)
  hipMemsetAsync(slots, 0, SLOT_BYTES, stream);

  gather_cast_kernel<<<SS * 4, 256, 0, stream>>>(idx, emb, xt);
  lstm_kernel<<<256, 64, 0, stream>>>(xt, slots, hT, Wih, Whh, bih, bhh);
  outproj_kernel<<<BB, 64, 0, stream>>>(hT, Wout, bout, y);
}